// Round 1
// baseline (2097.050 us; speedup 1.0000x reference)
//
#include <hip/hip_runtime.h>
#include <stdint.h>

#define Hd 1024
#define Bd 32
#define Td 64
#define Vd 32000
#define TB (Td*Bd)            // 2048
#define G3H 3072
static const size_t BTV = (size_t)Bd * Td * Vd;   // 65,536,000

typedef unsigned short u16;
typedef __attribute__((ext_vector_type(8))) short bf16x8;
typedef __attribute__((ext_vector_type(4))) float f32x4;

typedef __attribute__((address_space(3))) void lds_void;
typedef __attribute__((address_space(1))) const void gbl_void;

__device__ __forceinline__ void async_ld16(const void* g, void* l) {
    __builtin_amdgcn_global_load_lds((gbl_void*)g, (lds_void*)l, 16, 0, 0);
}

__device__ __forceinline__ u16 f2bf(float f) {
    union { float f; uint32_t u; } v; v.f = f;
    uint32_t u = v.u;
    return (u16)((u + 0x7fffu + ((u >> 16) & 1u)) >> 16);
}

// ---------------- fp32 -> bf16 convert (n4 = n/4 float4 groups) ----------------
__global__ void k_conv_bf16(const float* __restrict__ src, u16* __restrict__ dst, int n4) {
    int i = blockIdx.x * blockDim.x + threadIdx.x;
    if (i >= n4) return;
    float4 f = ((const float4*)src)[i];
    ushort4 o;
    o.x = f2bf(f.x); o.y = f2bf(f.y); o.z = f2bf(f.z); o.w = f2bf(f.w);
    ((ushort4*)dst)[i] = o;
}

// ---------------- embedding gather + relu + bf16 ----------------
__global__ void k_embed(const float* __restrict__ emb, const int* __restrict__ tgt,
                        u16* __restrict__ Xb) {
    int r = blockIdx.x;            // r = t*32 + b
    int t = r >> 5, b = r & 31;
    int tok = (t == 0) ? 1 : tgt[b * Td + (t - 1)];
    const float4* srow = (const float4*)(emb + (size_t)tok * Hd);
    int k = threadIdx.x;           // 256 threads * 4 floats = 1024
    float4 f = srow[k];
    ushort4 o;
    o.x = f2bf(fmaxf(f.x, 0.f)); o.y = f2bf(fmaxf(f.y, 0.f));
    o.z = f2bf(fmaxf(f.z, 0.f)); o.w = f2bf(fmaxf(f.w, 0.f));
    ((ushort4*)(Xb + (size_t)r * Hd))[k] = o;
}

// ---------------- h init: fp32 copy + bf16 copy ----------------
__global__ void k_init_h(const float* __restrict__ eh, float* __restrict__ h,
                         u16* __restrict__ hb) {
    int i = blockIdx.x * blockDim.x + threadIdx.x;   // 8192 float4s
    float4 f = ((const float4*)eh)[i];
    ((float4*)h)[i] = f;
    ushort4 o;
    o.x = f2bf(f.x); o.y = f2bf(f.y); o.z = f2bf(f.z); o.w = f2bf(f.w);
    ((ushort4*)hb)[i] = o;
}

// ---------------- 128x128 bf16 MFMA GEMM: C = A @ Bm^T + bias ----------------
// A [M,K] bf16 row-major, Bm [N,K] bf16 row-major, C fp32.
// MODE 0: C[m*N + n]           (gi)
// MODE 1: C[((b<<6)+t)*V + n]  with m = t*32+b  (logits into d_out [B,T,V])
template<int MODE>
__global__ __launch_bounds__(256, 2)
void k_gemm128(const u16* __restrict__ A, const u16* __restrict__ Bm,
               const float* __restrict__ bias, float* __restrict__ C,
               int N, int K)
{
    __shared__ alignas(16) u16 As[128 * 32];
    __shared__ alignas(16) u16 Bs[128 * 32];
    const int tid  = threadIdx.x;
    const int wave = tid >> 6;
    const int lane = tid & 63;
    const int l16  = lane & 15;
    const int q    = lane >> 4;
    const int wm   = (wave & 1) << 6;
    const int wn   = (wave >> 1) << 6;
    const int tm   = blockIdx.y << 7;
    const int tn   = blockIdx.x << 7;

    f32x4 acc[4][4];
#pragma unroll
    for (int i = 0; i < 4; ++i)
#pragma unroll
        for (int j = 0; j < 4; ++j) { f32x4 z = {0.f,0.f,0.f,0.f}; acc[i][j] = z; }

    // staging: 8 chunks of 16 rows each per matrix; wave w stages chunks 2w,2w+1.
    // chunk c, lane l -> row c*16 + (l>>2), k-group l&3 (8 bf16 = 16B)
    const int c0 = wave * 2, c1 = wave * 2 + 1;
    const int cr = lane >> 2;
    const int kg = lane & 3;
    const u16* gA0 = A + (size_t)(tm + c0*16 + cr) * K + kg*8;
    const u16* gA1 = A + (size_t)(tm + c1*16 + cr) * K + kg*8;
    const u16* gB0 = Bm + (size_t)(tn + c0*16 + cr) * K + kg*8;
    const u16* gB1 = Bm + (size_t)(tn + c1*16 + cr) * K + kg*8;
    u16* lA0 = &As[c0*512 + lane*8];
    u16* lA1 = &As[c1*512 + lane*8];
    u16* lB0 = &Bs[c0*512 + lane*8];
    u16* lB1 = &Bs[c1*512 + lane*8];

    for (int k0 = 0; k0 < K; k0 += 32) {
        async_ld16(gA0 + k0, lA0);
        async_ld16(gA1 + k0, lA1);
        async_ld16(gB0 + k0, lB0);
        async_ld16(gB1 + k0, lB1);
        __syncthreads();
        bf16x8 af[4], bfr[4];
#pragma unroll
        for (int i = 0; i < 4; ++i)
            af[i] = *(const bf16x8*)&As[(wm + i*16 + l16) * 32 + q*8];
#pragma unroll
        for (int j = 0; j < 4; ++j)
            bfr[j] = *(const bf16x8*)&Bs[(wn + j*16 + l16) * 32 + q*8];
#pragma unroll
        for (int i = 0; i < 4; ++i)
#pragma unroll
            for (int j = 0; j < 4; ++j)
                acc[i][j] = __builtin_amdgcn_mfma_f32_16x16x32_bf16(af[i], bfr[j], acc[i][j], 0, 0, 0);
        __syncthreads();
    }

#pragma unroll
    for (int i = 0; i < 4; ++i) {
        const int mbase = tm + wm + i*16 + q*4;
#pragma unroll
        for (int j = 0; j < 4; ++j) {
            const int n = tn + wn + j*16 + l16;
            const float bv = bias[n];
#pragma unroll
            for (int r = 0; r < 4; ++r) {
                const int m = mbase + r;
                const float v = acc[i][j][r] + bv;
                if (MODE == 0) {
                    C[(size_t)m * N + n] = v;
                } else {
                    const int tt = m >> 5, bb = m & 31;
                    C[(size_t)((bb << 6) + tt) * Vd + n] = v;
                }
            }
        }
    }
}

// ---------------- one GRU step: gh GEMM (MFMA, direct global) + fused gates ----------------
// grid 32 blocks x 256: block handles 32 hidden columns j0..j0+31 for all 32 batches.
__global__ void k_gru_step(const float* __restrict__ gi, float* __restrict__ h,
                           const u16* __restrict__ hb_in, u16* __restrict__ hb_out,
                           const u16* __restrict__ w_hhb, const float* __restrict__ b_hh,
                           u16* __restrict__ hsb, float* __restrict__ hlast, int t)
{
    __shared__ float ghs[3][32][32];
    const int tid  = threadIdx.x;
    const int wave = tid >> 6;
    const int lane = tid & 63;
    const int l16  = lane & 15;
    const int q    = lane >> 4;
    const int mh   = wave & 1;     // batch half
    const int nh   = wave >> 1;    // col half
    const int j0   = blockIdx.x << 5;

    f32x4 acc0 = {0.f,0.f,0.f,0.f}, acc1 = {0.f,0.f,0.f,0.f}, acc2 = {0.f,0.f,0.f,0.f};
    const u16* ap = hb_in + (size_t)(mh*16 + l16) * Hd + q*8;
    const int col = j0 + nh*16 + l16;
    const u16* bp0 = w_hhb + (size_t)(col)          * Hd + q*8;
    const u16* bp1 = w_hhb + (size_t)(Hd  + col)    * Hd + q*8;
    const u16* bp2 = w_hhb + (size_t)(2*Hd + col)   * Hd + q*8;
#pragma unroll 4
    for (int k = 0; k < Hd; k += 32) {
        bf16x8 a  = *(const bf16x8*)(ap  + k);
        bf16x8 w0 = *(const bf16x8*)(bp0 + k);
        bf16x8 w1 = *(const bf16x8*)(bp1 + k);
        bf16x8 w2 = *(const bf16x8*)(bp2 + k);
        acc0 = __builtin_amdgcn_mfma_f32_16x16x32_bf16(a, w0, acc0, 0, 0, 0);
        acc1 = __builtin_amdgcn_mfma_f32_16x16x32_bf16(a, w1, acc1, 0, 0, 0);
        acc2 = __builtin_amdgcn_mfma_f32_16x16x32_bf16(a, w2, acc2, 0, 0, 0);
    }
#pragma unroll
    for (int r = 0; r < 4; ++r) {
        const int bb = mh*16 + q*4 + r;
        const int jj = nh*16 + l16;
        ghs[0][bb][jj] = acc0[r];
        ghs[1][bb][jj] = acc1[r];
        ghs[2][bb][jj] = acc2[r];
    }
    __syncthreads();

    const int b  = tid >> 3;
    const int jl = (tid & 7) << 2;
    const int row = (t << 5) + b;
    const float* girow = gi + (size_t)row * G3H;
#pragma unroll
    for (int v = 0; v < 4; ++v) {
        const int jj = jl + v;
        const int j  = j0 + jj;
        const float gr = girow[j];
        const float gz = girow[Hd + j];
        const float gn = girow[2*Hd + j];
        const float hr = ghs[0][b][jj] + b_hh[j];
        const float hz = ghs[1][b][jj] + b_hh[Hd + j];
        const float hn = ghs[2][b][jj] + b_hh[2*Hd + j];
        const float rg = 1.f / (1.f + __expf(-(gr + hr)));
        const float zg = 1.f / (1.f + __expf(-(gz + hz)));
        const float ng = tanhf(gn + rg * hn);
        const float hp = h[b*Hd + j];
        const float hnew = (1.f - zg) * ng + zg * hp;
        h[b*Hd + j] = hnew;
        const u16 hv = f2bf(hnew);
        hb_out[b*Hd + j] = hv;
        hsb[(size_t)row * Hd + j] = hv;
        if (t == Td - 1) hlast[b*Hd + j] = hnew;
    }
}

// ---------------- in-place log-softmax over rows of 32000 ----------------
__global__ __launch_bounds__(256)
void k_logsoftmax(float* __restrict__ out) {
    float* row = out + (size_t)blockIdx.x * Vd;
    const int tid = threadIdx.x;
    float m = -1e30f, s = 0.f;
    for (int i = tid * 4; i + 3 < Vd; i += 1024) {
        float4 f = *(const float4*)(row + i);
        float lm = fmaxf(fmaxf(f.x, f.y), fmaxf(f.z, f.w));
        if (lm > m) { s *= __expf(m - lm); m = lm; }
        s += __expf(f.x - m) + __expf(f.y - m) + __expf(f.z - m) + __expf(f.w - m);
    }
    for (int off = 32; off > 0; off >>= 1) {
        float mo = __shfl_down(m, off, 64);
        float so = __shfl_down(s, off, 64);
        float M = fmaxf(m, mo);
        s = s * __expf(m - M) + so * __expf(mo - M);
        m = M;
    }
    __shared__ float sm[4], ss[4];
    const int wave = tid >> 6, lane = tid & 63;
    if (lane == 0) { sm[wave] = m; ss[wave] = s; }
    __syncthreads();
    const float M = fmaxf(fmaxf(sm[0], sm[1]), fmaxf(sm[2], sm[3]));
    const float S = ss[0]*__expf(sm[0]-M) + ss[1]*__expf(sm[1]-M)
                  + ss[2]*__expf(sm[2]-M) + ss[3]*__expf(sm[3]-M);
    const float lz = M + logf(S);
    for (int i = tid * 4; i + 3 < Vd; i += 1024) {
        float4 f = *(const float4*)(row + i);
        f.x -= lz; f.y -= lz; f.z -= lz; f.w -= lz;
        *(float4*)(row + i) = f;
    }
}

extern "C" void kernel_launch(void* const* d_in, const int* in_sizes, int n_in,
                              void* d_out, int out_size, void* d_ws, size_t ws_size,
                              hipStream_t stream) {
    const float* enc_h = (const float*)d_in[1];   // [1,B,H]
    const int*   tgt   = (const int*)d_in[2];     // [B,T]
    const float* emb   = (const float*)d_in[3];   // [V,H]
    const float* w_ih  = (const float*)d_in[4];   // [3H,H]
    const float* w_hh  = (const float*)d_in[5];   // [3H,H]
    const float* b_ih  = (const float*)d_in[6];   // [3H]
    const float* b_hh  = (const float*)d_in[7];   // [3H]
    const float* w_out = (const float*)d_in[8];   // [V,H]
    const float* b_out = (const float*)d_in[9];   // [V]
    float* out = (float*)d_out;

    char* ws = (char*)d_ws;
    size_t off = 0;
    auto alloc = [&](size_t bytes) { void* p = ws + off; off += (bytes + 255) & ~(size_t)255; return p; };
    u16*   w_outb = (u16*)  alloc((size_t)Vd * Hd * 2);     // 65.5 MB
    u16*   w_ihb  = (u16*)  alloc((size_t)G3H * Hd * 2);    // 6.3 MB
    u16*   w_hhb  = (u16*)  alloc((size_t)G3H * Hd * 2);    // 6.3 MB
    u16*   Xb     = (u16*)  alloc((size_t)TB * Hd * 2);     // 4.2 MB
    u16*   hsb    = (u16*)  alloc((size_t)TB * Hd * 2);     // 4.2 MB
    float* gi     = (float*)alloc((size_t)TB * G3H * 4);    // 25.2 MB
    float* h      = (float*)alloc((size_t)Bd * Hd * 4);
    u16*   hb0    = (u16*)  alloc((size_t)Bd * Hd * 2);
    u16*   hb1    = (u16*)  alloc((size_t)Bd * Hd * 2);
    (void)ws_size; (void)in_sizes; (void)n_in; (void)out_size;

    // weight conversions + embedding gather (parallel, no dependencies)
    k_conv_bf16<<<(Vd*Hd/4 + 255)/256, 256, 0, stream>>>(w_out, w_outb, Vd*Hd/4);
    k_conv_bf16<<<(G3H*Hd/4 + 255)/256, 256, 0, stream>>>(w_ih, w_ihb, G3H*Hd/4);
    k_conv_bf16<<<(G3H*Hd/4 + 255)/256, 256, 0, stream>>>(w_hh, w_hhb, G3H*Hd/4);
    k_embed<<<TB, 256, 0, stream>>>(emb, tgt, Xb);
    k_init_h<<<32, 256, 0, stream>>>(enc_h, h, hb0);

    // gi = relu(emb[tok]) @ w_ih^T + b_ih  for all T*B rows (parallel over t)
    k_gemm128<0><<<dim3(G3H/128, TB/128), 256, 0, stream>>>(Xb, w_ihb, b_ih, gi, G3H, Hd);

    // sequential GRU steps
    for (int t = 0; t < Td; ++t) {
        const u16* hin = (t & 1) ? hb1 : hb0;
        u16* hout      = (t & 1) ? hb0 : hb1;
        k_gru_step<<<32, 256, 0, stream>>>(gi, h, hin, hout, w_hhb, b_hh, hsb,
                                           out + BTV, t);
    }

    // logits = hs @ w_out^T + b_out  -> d_out[b][t][v]
    k_gemm128<1><<<dim3(Vd/128, TB/128), 256, 0, stream>>>(hsb, w_outb, b_out, out, Vd, Hd);

    // in-place log-softmax per (b,t) row
    k_logsoftmax<<<TB, 256, 0, stream>>>(out);
}

// Round 2
// 1314.225 us; speedup vs baseline: 1.5957x; 1.5957x over previous
//
#include <hip/hip_runtime.h>
#include <stdint.h>

#define Hd 1024
#define Bd 32
#define Td 64
#define Vd 32000
#define TB (Td*Bd)            // 2048
#define G3H 3072
#define NB 64                 // persistent-kernel blocks (<=256 CUs -> co-resident)
#define JC 16                 // h-columns per block
static const size_t BTV = (size_t)Bd * Td * Vd;   // 65,536,000

typedef unsigned short u16;
typedef __attribute__((ext_vector_type(8))) short bf16x8;
typedef __attribute__((ext_vector_type(4))) float f32x4;

typedef __attribute__((address_space(3))) void lds_void;
typedef __attribute__((address_space(1))) const void gbl_void;

__device__ __forceinline__ void async_ld16(const void* g, void* l) {
    __builtin_amdgcn_global_load_lds((gbl_void*)g, (lds_void*)l, 16, 0, 0);
}

__device__ __forceinline__ u16 f2bf(float f) {
    union { float f; uint32_t u; } v; v.f = f;
    uint32_t u = v.u;
    return (u16)((u + 0x7fffu + ((u >> 16) & 1u)) >> 16);
}

// ---------------- fp32 -> bf16 convert ----------------
__global__ void k_conv_bf16(const float* __restrict__ src, u16* __restrict__ dst, int n4) {
    int i = blockIdx.x * blockDim.x + threadIdx.x;
    if (i >= n4) return;
    float4 f = ((const float4*)src)[i];
    ushort4 o;
    o.x = f2bf(f.x); o.y = f2bf(f.y); o.z = f2bf(f.z); o.w = f2bf(f.w);
    ((ushort4*)dst)[i] = o;
}

// ---------------- embedding gather + relu + bf16 ----------------
__global__ void k_embed(const float* __restrict__ emb, const int* __restrict__ tgt,
                        u16* __restrict__ Xb) {
    int r = blockIdx.x;            // r = t*32 + b
    int t = r >> 5, b = r & 31;
    int tok = (t == 0) ? 1 : tgt[b * Td + (t - 1)];
    const float4* srow = (const float4*)(emb + (size_t)tok * Hd);
    int k = threadIdx.x;
    float4 f = srow[k];
    ushort4 o;
    o.x = f2bf(fmaxf(f.x, 0.f)); o.y = f2bf(fmaxf(f.y, 0.f));
    o.z = f2bf(fmaxf(f.z, 0.f)); o.w = f2bf(fmaxf(f.w, 0.f));
    ((ushort4*)(Xb + (size_t)r * Hd))[k] = o;
}

// ---------------- h init: bf16 copy + barrier-counter zero ----------------
__global__ void k_init_h(const float* __restrict__ eh, u16* __restrict__ hb,
                         unsigned int* __restrict__ cnt) {
    if (blockIdx.x == 0 && threadIdx.x == 0) *cnt = 0u;
    int i = blockIdx.x * blockDim.x + threadIdx.x;   // 8192 float4s
    float4 f = ((const float4*)eh)[i];
    ushort4 o;
    o.x = f2bf(f.x); o.y = f2bf(f.y); o.z = f2bf(f.z); o.w = f2bf(f.w);
    ((ushort4*)hb)[i] = o;
}

// ---------------- 128x128 bf16 MFMA GEMM: C = A @ Bm^T + bias ----------------
// MODE 0: C[m*N + n]           (gi)
// MODE 1: C[((b<<6)+t)*V + n]  with m = t*32+b  (logits into d_out [B,T,V])
// SWAP 1: blockIdx.x = m-tile (inner) for B-slab L2 reuse
template<int MODE, int SWAP>
__global__ __launch_bounds__(256, 2)
void k_gemm128(const u16* __restrict__ A, const u16* __restrict__ Bm,
               const float* __restrict__ bias, float* __restrict__ C,
               int N, int K)
{
    __shared__ alignas(16) u16 As[128 * 32];
    __shared__ alignas(16) u16 Bs[128 * 32];
    const int tid  = threadIdx.x;
    const int wave = tid >> 6;
    const int lane = tid & 63;
    const int l16  = lane & 15;
    const int q    = lane >> 4;
    const int wm   = (wave & 1) << 6;
    const int wn   = (wave >> 1) << 6;
    const int tm   = (SWAP ? blockIdx.x : blockIdx.y) << 7;
    const int tn   = (SWAP ? blockIdx.y : blockIdx.x) << 7;

    f32x4 acc[4][4];
#pragma unroll
    for (int i = 0; i < 4; ++i)
#pragma unroll
        for (int j = 0; j < 4; ++j) { f32x4 z = {0.f,0.f,0.f,0.f}; acc[i][j] = z; }

    const int c0 = wave * 2, c1 = wave * 2 + 1;
    const int cr = lane >> 2;
    const int kg = lane & 3;
    const u16* gA0 = A + (size_t)(tm + c0*16 + cr) * K + kg*8;
    const u16* gA1 = A + (size_t)(tm + c1*16 + cr) * K + kg*8;
    const u16* gB0 = Bm + (size_t)(tn + c0*16 + cr) * K + kg*8;
    const u16* gB1 = Bm + (size_t)(tn + c1*16 + cr) * K + kg*8;
    u16* lA0 = &As[c0*512 + lane*8];
    u16* lA1 = &As[c1*512 + lane*8];
    u16* lB0 = &Bs[c0*512 + lane*8];
    u16* lB1 = &Bs[c1*512 + lane*8];

    for (int k0 = 0; k0 < K; k0 += 32) {
        async_ld16(gA0 + k0, lA0);
        async_ld16(gA1 + k0, lA1);
        async_ld16(gB0 + k0, lB0);
        async_ld16(gB1 + k0, lB1);
        __syncthreads();
        bf16x8 af[4], bfr[4];
#pragma unroll
        for (int i = 0; i < 4; ++i)
            af[i] = *(const bf16x8*)&As[(wm + i*16 + l16) * 32 + q*8];
#pragma unroll
        for (int j = 0; j < 4; ++j)
            bfr[j] = *(const bf16x8*)&Bs[(wn + j*16 + l16) * 32 + q*8];
#pragma unroll
        for (int i = 0; i < 4; ++i)
#pragma unroll
            for (int j = 0; j < 4; ++j)
                acc[i][j] = __builtin_amdgcn_mfma_f32_16x16x32_bf16(af[i], bfr[j], acc[i][j], 0, 0, 0);
        __syncthreads();
    }

#pragma unroll
    for (int i = 0; i < 4; ++i) {
        const int mbase = tm + wm + i*16 + q*4;
#pragma unroll
        for (int j = 0; j < 4; ++j) {
            const int n = tn + wn + j*16 + l16;
            const float bv = bias[n];
#pragma unroll
            for (int r = 0; r < 4; ++r) {
                const int m = mbase + r;
                const float v = acc[i][j][r] + bv;
                if (MODE == 0) {
                    C[(size_t)m * N + n] = v;
                } else {
                    const int tt = m >> 5, bb = m & 31;
                    C[(size_t)((bb << 6) + tt) * Vd + n] = v;
                }
            }
        }
    }
}

// ---------------- persistent GRU recurrence ----------------
// NB=64 blocks x 256 threads, all co-resident. Block owns JC=16 h-columns
// (all 3 gates) -> pointwise is block-local -> ONE grid barrier per step.
// w_hh slice (48 rows x 1024) staged to LDS once; h state in registers.
__global__ __launch_bounds__(256, 1)
void k_gru_persist(const float* __restrict__ gi,
                   const float* __restrict__ enc_h,
                   const u16* __restrict__ w_hhb,
                   const float* __restrict__ b_hh,
                   u16* __restrict__ hbA, u16* __restrict__ hbB,
                   u16* __restrict__ hsb, float* __restrict__ hlast,
                   unsigned int* __restrict__ cnt)
{
    // Ws flat layout: element [(k>>3)*48 + g*16 + r]*8 + (k&7)  (16B units k-major)
    __shared__ alignas(16) u16 Ws[48 * 1024];          // 96 KB
    __shared__ float ghs[2][3][32][JC];                // 12 KB (kh-partials)
    const int tid = threadIdx.x;
    const int j0  = blockIdx.x * JC;

    // stage weight slice once: rows {g*1024 + j0 + r}, g=0..2, r=0..15
    for (int idx = tid; idx < 48 * 128; idx += 256) {
        int gr = idx >> 7;          // 0..47 = g*16 + r
        int c  = idx & 127;         // 16B k-chunk
        const u16* src = w_hhb + (size_t)((gr >> 4) * Hd + j0 + (gr & 15)) * Hd + c * 8;
        *(bf16x8*)&Ws[(size_t)(c * 48 + gr) * 8] = *(const bf16x8*)src;
    }

    // pointwise mapping: thread -> (batch b, columns jp, jp+1)
    const int b  = tid >> 3;
    const int jp = (tid & 7) * 2;
    float h0 = enc_h[b * Hd + j0 + jp];
    float h1 = enc_h[b * Hd + j0 + jp + 1];
    const float br0 = b_hh[j0 + jp],           br1 = b_hh[j0 + jp + 1];
    const float bz0 = b_hh[Hd + j0 + jp],      bz1 = b_hh[Hd + j0 + jp + 1];
    const float bn0 = b_hh[2*Hd + j0 + jp],    bn1 = b_hh[2*Hd + j0 + jp + 1];

    // wave roles: mh = batch half, kh = K half
    const int wave = tid >> 6, lane = tid & 63;
    const int l16 = lane & 15, q = lane >> 4;
    const int mh = wave & 1, kh = wave >> 1;

    __syncthreads();   // Ws ready

    for (int t = 0; t < Td; ++t) {
        const u16* hb_in = (t & 1) ? hbB : hbA;
        u16*       hb_out = (t & 1) ? hbA : hbB;
        const int row = t * 32 + b;
        const float* gir = gi + (size_t)row * G3H;
        // prefetch gi (independent of h) — stays in flight during GEMM
        const float gr0 = gir[j0 + jp],          gr1 = gir[j0 + jp + 1];
        const float gz0 = gir[Hd + j0 + jp],     gz1 = gir[Hd + j0 + jp + 1];
        const float gn0 = gir[2*Hd + j0 + jp],   gn1 = gir[2*Hd + j0 + jp + 1];

        // gh GEMM: [32 x 1024] @ [48 x 1024]^T, split K across kh
        f32x4 acc0 = {0.f,0.f,0.f,0.f}, acc1 = acc0, acc2 = acc0;
        const u16* ap = hb_in + (size_t)(mh*16 + l16) * Hd + kh*512 + q*8;
#pragma unroll
        for (int it = 0; it < 16; ++it) {
            bf16x8 a = *(const bf16x8*)(ap + it*32);
            const int kgrp = kh*64 + it*4 + q;
            const u16* wp = &Ws[(size_t)(kgrp * 48 + l16) * 8];
            bf16x8 w0 = *(const bf16x8*)(wp);
            bf16x8 w1 = *(const bf16x8*)(wp + 16*8);
            bf16x8 w2 = *(const bf16x8*)(wp + 32*8);
            acc0 = __builtin_amdgcn_mfma_f32_16x16x32_bf16(a, w0, acc0, 0, 0, 0);
            acc1 = __builtin_amdgcn_mfma_f32_16x16x32_bf16(a, w1, acc1, 0, 0, 0);
            acc2 = __builtin_amdgcn_mfma_f32_16x16x32_bf16(a, w2, acc2, 0, 0, 0);
        }
#pragma unroll
        for (int r = 0; r < 4; ++r) {
            const int bb = mh*16 + q*4 + r;
            ghs[kh][0][bb][l16] = acc0[r];
            ghs[kh][1][bb][l16] = acc1[r];
            ghs[kh][2][bb][l16] = acc2[r];
        }
        __syncthreads();

        // fused gates (block-local: this block owns these 16 columns)
        {
            const float hr0 = ghs[0][0][b][jp]   + ghs[1][0][b][jp]   + br0;
            const float hr1 = ghs[0][0][b][jp+1] + ghs[1][0][b][jp+1] + br1;
            const float hz0 = ghs[0][1][b][jp]   + ghs[1][1][b][jp]   + bz0;
            const float hz1 = ghs[0][1][b][jp+1] + ghs[1][1][b][jp+1] + bz1;
            const float hn0 = ghs[0][2][b][jp]   + ghs[1][2][b][jp]   + bn0;
            const float hn1 = ghs[0][2][b][jp+1] + ghs[1][2][b][jp+1] + bn1;
            const float rg0 = 1.f / (1.f + __expf(-(gr0 + hr0)));
            const float rg1 = 1.f / (1.f + __expf(-(gr1 + hr1)));
            const float zg0 = 1.f / (1.f + __expf(-(gz0 + hz0)));
            const float zg1 = 1.f / (1.f + __expf(-(gz1 + hz1)));
            const float ng0 = tanhf(gn0 + rg0 * hn0);
            const float ng1 = tanhf(gn1 + rg1 * hn1);
            h0 = (1.f - zg0) * ng0 + zg0 * h0;
            h1 = (1.f - zg1) * ng1 + zg1 * h1;
            ushort2 pv; pv.x = f2bf(h0); pv.y = f2bf(h1);
            *(ushort2*)&hb_out[b * Hd + j0 + jp] = pv;
            *(ushort2*)&hsb[(size_t)row * Hd + j0 + jp] = pv;
            if (t == Td - 1) {
                hlast[b * Hd + j0 + jp]     = h0;
                hlast[b * Hd + j0 + jp + 1] = h1;
            }
        }

        if (t < Td - 1) {
            __syncthreads();                       // all block stores issued+drained
            if (tid == 0) {
                __threadfence();                   // release: wb to coherence point
                atomicAdd(cnt, 1u);
                const unsigned tgt = (unsigned)(t + 1) * NB;
                while (__hip_atomic_load(cnt, __ATOMIC_RELAXED, __HIP_MEMORY_SCOPE_AGENT) < tgt)
                    __builtin_amdgcn_s_sleep(1);
                __threadfence();                   // acquire: invalidate L1/L2
            }
            __syncthreads();
        }
    }
}

// ---------------- in-place log-softmax over rows of 32000 ----------------
__global__ __launch_bounds__(256)
void k_logsoftmax(float* __restrict__ out) {
    float* row = out + (size_t)blockIdx.x * Vd;
    const int tid = threadIdx.x;
    float m = -1e30f, s = 0.f;
    for (int i = tid * 4; i + 3 < Vd; i += 1024) {
        float4 f = *(const float4*)(row + i);
        float lm = fmaxf(fmaxf(f.x, f.y), fmaxf(f.z, f.w));
        if (lm > m) { s *= __expf(m - lm); m = lm; }
        s += __expf(f.x - m) + __expf(f.y - m) + __expf(f.z - m) + __expf(f.w - m);
    }
    for (int off = 32; off > 0; off >>= 1) {
        float mo = __shfl_down(m, off, 64);
        float so = __shfl_down(s, off, 64);
        float M = fmaxf(m, mo);
        s = s * __expf(m - M) + so * __expf(mo - M);
        m = M;
    }
    __shared__ float sm[4], ss[4];
    const int wave = tid >> 6, lane = tid & 63;
    if (lane == 0) { sm[wave] = m; ss[wave] = s; }
    __syncthreads();
    const float M = fmaxf(fmaxf(sm[0], sm[1]), fmaxf(sm[2], sm[3]));
    const float S = ss[0]*__expf(sm[0]-M) + ss[1]*__expf(sm[1]-M)
                  + ss[2]*__expf(sm[2]-M) + ss[3]*__expf(sm[3]-M);
    const float lz = M + logf(S);
    for (int i = tid * 4; i + 3 < Vd; i += 1024) {
        float4 f = *(const float4*)(row + i);
        f.x -= lz; f.y -= lz; f.z -= lz; f.w -= lz;
        *(float4*)(row + i) = f;
    }
}

extern "C" void kernel_launch(void* const* d_in, const int* in_sizes, int n_in,
                              void* d_out, int out_size, void* d_ws, size_t ws_size,
                              hipStream_t stream) {
    const float* enc_h = (const float*)d_in[1];   // [1,B,H]
    const int*   tgt   = (const int*)d_in[2];     // [B,T]
    const float* emb   = (const float*)d_in[3];   // [V,H]
    const float* w_ih  = (const float*)d_in[4];   // [3H,H]
    const float* w_hh  = (const float*)d_in[5];   // [3H,H]
    const float* b_ih  = (const float*)d_in[6];   // [3H]
    const float* b_hh  = (const float*)d_in[7];   // [3H]
    const float* w_out = (const float*)d_in[8];   // [V,H]
    const float* b_out = (const float*)d_in[9];   // [V]
    float* out = (float*)d_out;

    char* ws = (char*)d_ws;
    size_t off = 0;
    auto alloc = [&](size_t bytes) { void* p = ws + off; off += (bytes + 255) & ~(size_t)255; return p; };
    u16*   w_outb = (u16*)  alloc((size_t)Vd * Hd * 2);     // 65.5 MB
    u16*   w_ihb  = (u16*)  alloc((size_t)G3H * Hd * 2);    // 6.3 MB
    u16*   w_hhb  = (u16*)  alloc((size_t)G3H * Hd * 2);    // 6.3 MB
    u16*   Xb     = (u16*)  alloc((size_t)TB * Hd * 2);     // 4.2 MB
    u16*   hsb    = (u16*)  alloc((size_t)TB * Hd * 2);     // 4.2 MB
    float* gi     = (float*)alloc((size_t)TB * G3H * 4);    // 25.2 MB
    u16*   hb0    = (u16*)  alloc((size_t)Bd * Hd * 2);
    u16*   hb1    = (u16*)  alloc((size_t)Bd * Hd * 2);
    unsigned int* cnt = (unsigned int*) alloc(256);
    (void)ws_size; (void)in_sizes; (void)n_in; (void)out_size;

    // weight conversions + embedding gather (parallel, no dependencies)
    k_conv_bf16<<<(Vd*Hd/4 + 255)/256, 256, 0, stream>>>(w_out, w_outb, Vd*Hd/4);
    k_conv_bf16<<<(G3H*Hd/4 + 255)/256, 256, 0, stream>>>(w_ih, w_ihb, G3H*Hd/4);
    k_conv_bf16<<<(G3H*Hd/4 + 255)/256, 256, 0, stream>>>(w_hh, w_hhb, G3H*Hd/4);
    k_embed<<<TB, 256, 0, stream>>>(emb, tgt, Xb);
    k_init_h<<<32, 256, 0, stream>>>(enc_h, hb0, cnt);

    // gi = relu(emb[tok]) @ w_ih^T + b_ih  for all T*B rows
    k_gemm128<0,0><<<dim3(G3H/128, TB/128), 256, 0, stream>>>(Xb, w_ihb, b_ih, gi, G3H, Hd);

    // full recurrence in ONE persistent kernel (64 blocks, grid barrier per step)
    k_gru_persist<<<NB, 256, 0, stream>>>(gi, enc_h, w_hhb, b_hh, hb0, hb1, hsb,
                                          out + BTV, cnt);

    // logits = hs @ w_out^T + b_out -> d_out[b][t][v]; m-tiles inner for w reuse
    k_gemm128<1,1><<<dim3(TB/128, Vd/128), 256, 0, stream>>>(hsb, w_outb, b_out, out, Vd, Hd);

    // in-place log-softmax per (b,t) row
    k_logsoftmax<<<TB, 256, 0, stream>>>(out);
}